// Round 10
// baseline (68.291 us; speedup 1.0000x reference)
//
#include <hip/hip_runtime.h>
#include <hip/hip_bf16.h>
#include <stdint.h>

static constexpr int P_N   = 16384;
static constexpr int D_Z   = 512;
static constexpr int D_PHI = 256;
static constexpr int D_R   = 64;
static constexpr int H     = 96;    // H1 == H2
static constexpr int KP    = 832;   // 3*D_PHI + D_R

using f32x4 = __attribute__((ext_vector_type(4))) float;
using s16x8 = __attribute__((ext_vector_type(8))) short;

__device__ __forceinline__ unsigned short f2bf(float f) {
    union { float f; uint32_t u; } v; v.f = f;
    return (unsigned short)((v.u + 0x7FFFu + ((v.u >> 16) & 1u)) >> 16);
}

// packed RNE f32x2 -> bf16x2 (v_cvt_pk_bf16_f32)
__device__ __forceinline__ uint32_t pkbf2(float lo, float hi) {
    union { __hip_bfloat162 h; uint32_t u; } c;
    c.h = __float22bfloat162_rn(make_float2(lo, hi));
    return c.u;
}

// gelu(x) ~= x * sigmoid(1.5957691*(x + 0.044715 x^3))
//         =  x * rcp(1 + exp2(x*(-2.3022126 - 0.1029444 x^2)))
__device__ __forceinline__ float gelu_f(float x) {
    float x2 = x * x;
    float u  = __builtin_fmaf(-0.1029444f, x2, -2.3022126f);
    float e  = __builtin_amdgcn_exp2f(x * u);
    return x * __builtin_amdgcn_rcpf(1.0f + e);
}

// ---------------------------------------------------------------------------
// prep: fragment-contiguous weight layouts so every consumer B-load is
//       base + lane*16B (fully coalesced).
//  blocks 0..15  : gqfrag[((n>>5)*64 + ((n>>3)&3)*16 + b)*8 + (n&7)]
//                  = g_q[b] @ W1[:512][n] + b1[n]     (f32)
//  blocks 16..327: W1frag[((nf*26+kc)*64 + l)*8 + ke] = bf16(W1[512+k][n])
//                  n = nf*16 + (l&15), k = kc*32 + (l>>4)*8 + ke
//  blocks 328..363: W2frag[((nf*3+ks)*64 + l)*8 + ke] = bf16(W2[k][n])
// ---------------------------------------------------------------------------
__global__ __launch_bounds__(256) void prep_kernel(
    const float* __restrict__ g_q, const float* __restrict__ W1,
    const float* __restrict__ b1, const float* __restrict__ W2,
    float* __restrict__ gqfrag, unsigned short* __restrict__ W1frag,
    unsigned short* __restrict__ W2frag)
{
    __shared__ float gql[D_Z];
    __shared__ float red[192];
    const int blk = blockIdx.x;
    const int t = threadIdx.x;
    if (blk < 16) {
        const int b = blk;
        for (int i = t; i < D_Z; i += 256) gql[i] = g_q[b * D_Z + i];
        __syncthreads();
        float acc = 0.f;
        if (t < 192) {
            const int n = t % 96, s = t / 96;
            const int k0 = s * 256;
            #pragma unroll 8
            for (int k = 0; k < 256; ++k)
                acc += gql[k0 + k] * W1[(k0 + k) * H + n];
            red[t] = acc;
        }
        __syncthreads();
        if (t < 96) {
            const float v = red[t] + red[t + 96] + b1[t];
            const int dst = ((t >> 5) * 64 + ((t >> 3) & 3) * 16 + b) * 8 + (t & 7);
            gqfrag[dst] = v;
        }
    } else if (blk < 328) {
        const int e = (blk - 16) * 256 + t;           // < 96*832
        const int n = e / KP, k = e % KP;
        const int nf = n >> 4, lr = n & 15;
        const int kc = k >> 5, l4 = (k >> 3) & 3, ke = k & 7;
        W1frag[((nf * 26 + kc) * 64 + l4 * 16 + lr) * 8 + ke] =
            f2bf(W1[(D_Z + k) * H + n]);
    } else {
        const int e = (blk - 328) * 256 + t;          // < 96*96
        const int n = e / H, k = e % H;
        const int nf = n >> 4, lr = n & 15;
        const int ks = k >> 5, l4 = (k >> 3) & 3, ke = k & 7;
        W2frag[((nf * 3 + ks) * 64 + l4 * 16 + lr) * 8 + ke] =
            f2bf(W2[k * H + n]);
    }
}

// ---------------------------------------------------------------------------
// fused8: 8 pairs x 16 b per 256-thr block (4 waves), grid 2048.
//  NO feats LDS, NO phase-0 barrier.  Layer-1 A-frags built in registers:
//  lane l owns pair (lr&7), k-chunk l4; one PI/PJ load pair feeds the
//  sum / |diff| / prod fragments.  Wave (kh=w&1, ng=w>>1): 3 n-frags,
//  kc half kh.  #pragma unroll 1 keeps live loads to one iteration.
//  Partials -> y1part[kh][8][100] (6.4KB), ONE barrier, then phase 2 per-mf:
//  afr[3] = bf16(gelu(gq + y1h0 + y1h1)); 18 MFMA vs W2frag; gelu -> dot W3;
//  shfl-reduce -> out.
// ---------------------------------------------------------------------------
__global__ __launch_bounds__(256, 3) void fused8_kernel(
    const float* __restrict__ Phi, const int* __restrict__ pidx,
    const float* __restrict__ rel, const unsigned short* __restrict__ W1frag,
    const float* __restrict__ gqfrag, const unsigned short* __restrict__ W2frag,
    const float* __restrict__ b2, const float* __restrict__ W3,
    const float* __restrict__ b3, float* __restrict__ out)
{
    __shared__ __align__(16) float y1part[2][8][100];   // padded stride
    const int t = threadIdx.x;
    const int w = t >> 6, l = t & 63;
    const int lr = l & 15, l4 = l >> 4;
    const int kh = w & 1, ng = w >> 1;
    const int p0 = blockIdx.x * 8;
    const int pair = lr & 7;                 // rows 8..15 duplicate 0..7

    const int2 ij = *(const int2*)(pidx + 2 * (p0 + pair));
    const float* PI = Phi + (long)ij.x * D_PHI + l4 * 8;
    const float* PJ = Phi + (long)ij.y * D_PHI + l4 * 8;

    f32x4 acc[3];
    acc[0] = (f32x4){0.f,0.f,0.f,0.f};
    acc[1] = (f32x4){0.f,0.f,0.f,0.f};
    acc[2] = (f32x4){0.f,0.f,0.f,0.f};

    auto mk8 = [](float x0,float x1,float x2,float x3,
                  float x4,float x5,float x6,float x7) -> s16x8 {
        union { s16x8 v; uint32_t u[4]; } pk;
        pk.u[0] = pkbf2(x0, x1); pk.u[1] = pkbf2(x2, x3);
        pk.u[2] = pkbf2(x4, x5); pk.u[3] = pkbf2(x6, x7);
        return pk.v;
    };
    #define MFMA3(aa, kc)                                                     \
        {                                                                     \
            _Pragma("unroll")                                                 \
            for (int j = 0; j < 3; ++j) {                                     \
                const s16x8 bb = *(const s16x8*)(W1frag +                     \
                    (((ng * 3 + j) * 26 + (kc)) * 64 + l) * 8);               \
                acc[j] = __builtin_amdgcn_mfma_f32_16x16x32_bf16(aa, bb, acc[j], 0, 0, 0); \
            }                                                                 \
        }

    if (kh == 0) {
        // kc 0..7: sum (kb 0..255); kc 8..12: |diff| (kb 0..159)
        #pragma unroll 1
        for (int i = 0; i < 8; ++i) {
            const int kb = i * 32;
            float4 a0 = *(const float4*)(PI + kb), a1 = *(const float4*)(PI + kb + 4);
            float4 c0 = *(const float4*)(PJ + kb), c1 = *(const float4*)(PJ + kb + 4);
            s16x8 as = mk8(a0.x+c0.x, a0.y+c0.y, a0.z+c0.z, a0.w+c0.w,
                           a1.x+c1.x, a1.y+c1.y, a1.z+c1.z, a1.w+c1.w);
            MFMA3(as, i);
            if (i < 5) {
                s16x8 ad = mk8(fabsf(a0.x-c0.x), fabsf(a0.y-c0.y), fabsf(a0.z-c0.z), fabsf(a0.w-c0.w),
                               fabsf(a1.x-c1.x), fabsf(a1.y-c1.y), fabsf(a1.z-c1.z), fabsf(a1.w-c1.w));
                MFMA3(ad, 8 + i);
            }
        }
    } else {
        // kc 16..23: prod (kb 0..255); kc 13..15: |diff| (kb 160..255)
        #pragma unroll 1
        for (int i = 0; i < 8; ++i) {
            const int kb = i * 32;
            float4 a0 = *(const float4*)(PI + kb), a1 = *(const float4*)(PI + kb + 4);
            float4 c0 = *(const float4*)(PJ + kb), c1 = *(const float4*)(PJ + kb + 4);
            s16x8 ap = mk8(a0.x*c0.x, a0.y*c0.y, a0.z*c0.z, a0.w*c0.w,
                           a1.x*c1.x, a1.y*c1.y, a1.z*c1.z, a1.w*c1.w);
            MFMA3(ap, 16 + i);
            if (i >= 5) {
                s16x8 ad = mk8(fabsf(a0.x-c0.x), fabsf(a0.y-c0.y), fabsf(a0.z-c0.z), fabsf(a0.w-c0.w),
                               fabsf(a1.x-c1.x), fabsf(a1.y-c1.y), fabsf(a1.z-c1.z), fabsf(a1.w-c1.w));
                MFMA3(ad, 13 + (i - 5));
            }
        }
        // kc 24..25: relation features
        const float* PR = rel + (long)(p0 + pair) * D_R + l4 * 8;
        #pragma unroll 1
        for (int i = 0; i < 2; ++i) {
            float4 r0 = *(const float4*)(PR + i * 32), r1 = *(const float4*)(PR + i * 32 + 4);
            s16x8 ar = mk8(r0.x, r0.y, r0.z, r0.w, r1.x, r1.y, r1.z, r1.w);
            MFMA3(ar, 24 + i);
        }
    }
    #undef MFMA3

    if (l4 < 2) {   // rows 8..15 duplicate rows 0..7; store 0..7 only
        #pragma unroll
        for (int j = 0; j < 3; ++j)
            #pragma unroll
            for (int r = 0; r < 4; ++r)
                y1part[kh][l4 * 4 + r][ng * 48 + j * 16 + lr] = acc[j][r];
    }
    __syncthreads();

    // phase 2: pairs 2w, 2w+1, one mf at a time (register-lean)
    float part[2][4];
    #pragma unroll
    for (int mf = 0; mf < 2; ++mf) {
        const int pl = 2 * w + mf;

        // 2a: A-fragments in consumer layout (row lr = b)
        s16x8 afr[3];
        #pragma unroll
        for (int ks = 0; ks < 3; ++ks) {
            const int c = ks * 32 + l4 * 8;
            const float* gp = gqfrag + (ks * 64 + l) * 8;
            float4 g0 = *(const float4*)gp, g1 = *(const float4*)(gp + 4);
            const float* ya = &y1part[0][pl][c];    // broadcast reads
            const float* yb = &y1part[1][pl][c];
            float4 u0 = *(const float4*)ya, u1 = *(const float4*)(ya + 4);
            float4 v0 = *(const float4*)yb, v1 = *(const float4*)(yb + 4);
            union { s16x8 v; uint32_t u[4]; } pk;
            pk.u[0] = pkbf2(gelu_f(g0.x + u0.x + v0.x), gelu_f(g0.y + u0.y + v0.y));
            pk.u[1] = pkbf2(gelu_f(g0.z + u0.z + v0.z), gelu_f(g0.w + u0.w + v0.w));
            pk.u[2] = pkbf2(gelu_f(g1.x + u1.x + v1.x), gelu_f(g1.y + u1.y + v1.y));
            pk.u[3] = pkbf2(gelu_f(g1.z + u1.z + v1.z), gelu_f(g1.w + u1.w + v1.w));
            afr[ks] = pk.v;
        }

        // 2b: layer-2 MFMA vs W2frag (L1-hot), acc init = b2
        f32x4 acc2[6];
        #pragma unroll
        for (int nf = 0; nf < 6; ++nf) {
            const float bv = b2[nf * 16 + lr];
            acc2[nf] = (f32x4){bv, bv, bv, bv};
        }
        #pragma unroll
        for (int ks = 0; ks < 3; ++ks) {
            #pragma unroll
            for (int nf = 0; nf < 6; ++nf) {
                const s16x8 bb = *(const s16x8*)(W2frag + ((nf * 3 + ks) * 64 + l) * 8);
                acc2[nf] = __builtin_amdgcn_mfma_f32_16x16x32_bf16(afr[ks], bb, acc2[nf], 0, 0, 0);
            }
        }

        // 2c: gelu -> dot W3
        part[mf][0] = part[mf][1] = part[mf][2] = part[mf][3] = 0.f;
        #pragma unroll
        for (int nf = 0; nf < 6; ++nf) {
            const float wv = W3[nf * 16 + lr];
            #pragma unroll
            for (int r4 = 0; r4 < 4; ++r4)
                part[mf][r4] = __builtin_fmaf(gelu_f(acc2[nf][r4]), wv, part[mf][r4]);
        }
    }

    // reduce over 16 col-lanes -> store
    #pragma unroll
    for (int mask = 1; mask <= 8; mask <<= 1)
        #pragma unroll
        for (int mf = 0; mf < 2; ++mf)
            #pragma unroll
            for (int r4 = 0; r4 < 4; ++r4)
                part[mf][r4] += __shfl_xor(part[mf][r4], mask, 64);
    if (lr == 0) {
        const float b3v = b3[0];
        #pragma unroll
        for (int mf = 0; mf < 2; ++mf)
            #pragma unroll
            for (int r4 = 0; r4 < 4; ++r4)
                out[(l4 * 4 + r4) * P_N + p0 + 2 * w + mf] = part[mf][r4] + b3v;
    }
}

extern "C" void kernel_launch(void* const* d_in, const int* in_sizes, int n_in,
                              void* d_out, int out_size, void* d_ws, size_t ws_size,
                              hipStream_t stream)
{
    const float* g_q  = (const float*)d_in[0];
    const float* Phi  = (const float*)d_in[1];
    const int*   pidx = (const int*)d_in[2];
    const float* rel  = (const float*)d_in[3];
    const float* W1   = (const float*)d_in[4];
    const float* b1   = (const float*)d_in[5];
    const float* W2   = (const float*)d_in[6];
    const float* b2   = (const float*)d_in[7];
    const float* W3   = (const float*)d_in[8];
    const float* b3   = (const float*)d_in[9];
    float* out = (float*)d_out;

    char* ws = (char*)d_ws;
    float*          gqfrag = (float*)(ws + 0);               // 3*64*8 f32 = 6KB
    unsigned short* W1frag = (unsigned short*)(ws + 8192);   // 96*832*2
    unsigned short* W2frag = (unsigned short*)(ws + 167936); // 96*96*2

    hipLaunchKernelGGL(prep_kernel, dim3(364), dim3(256), 0, stream,
                       g_q, W1, b1, W2, gqfrag, W1frag, W2frag);
    hipLaunchKernelGGL(fused8_kernel, dim3(P_N / 8), dim3(256), 0, stream,
                       Phi, pidx, rel, W1frag, gqfrag, W2frag, b2, W3, b3, out);
}

// Round 11
// 44.059 us; speedup vs baseline: 1.5500x; 1.5500x over previous
//
#include <hip/hip_runtime.h>
#include <hip/hip_bf16.h>
#include <stdint.h>

static constexpr int P_N   = 16384;
static constexpr int D_Z   = 512;
static constexpr int D_PHI = 256;
static constexpr int D_R   = 64;
static constexpr int H     = 96;    // H1 == H2
static constexpr int KP    = 832;   // 3*D_PHI + D_R

using f32x4 = __attribute__((ext_vector_type(4))) float;
using s16x8 = __attribute__((ext_vector_type(8))) short;

__device__ __forceinline__ unsigned short f2bf(float f) {
    union { float f; uint32_t u; } v; v.f = f;
    return (unsigned short)((v.u + 0x7FFFu + ((v.u >> 16) & 1u)) >> 16);
}

// packed RNE f32x2 -> bf16x2 (v_cvt_pk_bf16_f32)
__device__ __forceinline__ uint32_t pkbf2(float lo, float hi) {
    union { __hip_bfloat162 h; uint32_t u; } c;
    c.h = __float22bfloat162_rn(make_float2(lo, hi));
    return c.u;
}

// gelu(x) ~= x * sigmoid(1.5957691*(x + 0.044715 x^3))
//         =  x * rcp(1 + exp2(x*(-2.3022126 - 0.1029444 x^2)))
__device__ __forceinline__ float gelu_f(float x) {
    float x2 = x * x;
    float u  = __builtin_fmaf(-0.1029444f, x2, -2.3022126f);
    float e  = __builtin_amdgcn_exp2f(x * u);
    return x * __builtin_amdgcn_rcpf(1.0f + e);
}

// ---------------------------------------------------------------------------
// prep: fragment-contiguous weight layouts so every consumer B-load is
//       base + lane*16B (fully coalesced).
//  blocks 0..15  : gqfrag[((n>>5)*64 + ((n>>3)&3)*16 + b)*8 + (n&7)]
//                  = g_q[b] @ W1[:512][n] + b1[n]     (f32)
//  blocks 16..327: W1frag[((nf*26+kc)*64 + l)*8 + ke] = bf16(W1[512+k][n])
//                  n = nf*16 + (l&15), k = kc*32 + (l>>4)*8 + ke
//  blocks 328..363: W2frag[((nf*3+ks)*64 + l)*8 + ke] = bf16(W2[k][n])
// ---------------------------------------------------------------------------
__global__ __launch_bounds__(256) void prep_kernel(
    const float* __restrict__ g_q, const float* __restrict__ W1,
    const float* __restrict__ b1, const float* __restrict__ W2,
    float* __restrict__ gqfrag, unsigned short* __restrict__ W1frag,
    unsigned short* __restrict__ W2frag)
{
    __shared__ float gql[D_Z];
    __shared__ float red[192];
    const int blk = blockIdx.x;
    const int t = threadIdx.x;
    if (blk < 16) {
        const int b = blk;
        for (int i = t; i < D_Z; i += 256) gql[i] = g_q[b * D_Z + i];
        __syncthreads();
        float acc = 0.f;
        if (t < 192) {
            const int n = t % 96, s = t / 96;
            const int k0 = s * 256;
            #pragma unroll 8
            for (int k = 0; k < 256; ++k)
                acc += gql[k0 + k] * W1[(k0 + k) * H + n];
            red[t] = acc;
        }
        __syncthreads();
        if (t < 96) {
            const float v = red[t] + red[t + 96] + b1[t];
            const int dst = ((t >> 5) * 64 + ((t >> 3) & 3) * 16 + b) * 8 + (t & 7);
            gqfrag[dst] = v;
        }
    } else if (blk < 328) {
        const int e = (blk - 16) * 256 + t;           // < 96*832
        const int n = e / KP, k = e % KP;
        const int nf = n >> 4, lr = n & 15;
        const int kc = k >> 5, l4 = (k >> 3) & 3, ke = k & 7;
        W1frag[((nf * 26 + kc) * 64 + l4 * 16 + lr) * 8 + ke] =
            f2bf(W1[(D_Z + k) * H + n]);
    } else {
        const int e = (blk - 328) * 256 + t;          // < 96*96
        const int n = e / H, k = e % H;
        const int nf = n >> 4, lr = n & 15;
        const int ks = k >> 5, l4 = (k >> 3) & 3, ke = k & 7;
        W2frag[((nf * 3 + ks) * 64 + l4 * 16 + lr) * 8 + ke] =
            f2bf(W2[k * H + n]);
    }
}

// ---------------------------------------------------------------------------
// fused9: 16 pairs x 16 b per 512-thr block (8 waves), grid 1024.
//  ph0 : feats[16][832] bf16 in LDS (stride 840)
//  ph1 : all 8 waves: (kq=w&3, ng=w>>2): 3 n-frags x kc-chunk {7,7,6,6};
//        partials -> y1part[kq][16][100] f32 (summed at read)
//  ph2 : wave w -> pairs 2w, 2w+1, one mf at a time (register-lean):
//        afr[3] = bf16(gelu(gq + sum of 4 y1 partials)); 18 MFMA vs W2frag;
//        gelu -> dot W3; shfl-reduce -> out.
//  LDS 52.5KB -> 3 blocks/CU; target VGPR <= ~96 -> up to 24 waves/CU.
// ---------------------------------------------------------------------------
__global__ __launch_bounds__(512, 2) void fused9_kernel(
    const float* __restrict__ Phi, const int* __restrict__ pidx,
    const float* __restrict__ rel, const unsigned short* __restrict__ W1frag,
    const float* __restrict__ gqfrag, const unsigned short* __restrict__ W2frag,
    const float* __restrict__ b2, const float* __restrict__ W3,
    const float* __restrict__ b3, float* __restrict__ out)
{
    constexpr int FS = 840;                       // feats stride (shorts)
    __shared__ __align__(16) unsigned short feats[16 * FS];   // 26880 B
    __shared__ __align__(16) float y1part[4][16][100];        // 25600 B
    const int t = threadIdx.x;
    const int p0 = blockIdx.x * 16;

    // phase 0: 16 pairs x 104 chunks of 8 elems (1664 tasks / 512 thr)
    for (int task = t; task < 1664; task += 512) {
        const int pair = task / 104;
        const int k = (task - pair * 104) * 8;
        float f[8];
        if (k < 768) {
            const int2 ij = *(const int2*)(pidx + 2 * (p0 + pair));
            const int kb = k & 255;
            const float* PI = Phi + (long)ij.x * D_PHI + kb;
            const float* PJ = Phi + (long)ij.y * D_PHI + kb;
            float4 a0 = *(const float4*)PI, a1 = *(const float4*)(PI + 4);
            float4 c0 = *(const float4*)PJ, c1 = *(const float4*)(PJ + 4);
            if (k < 256) {
                f[0]=a0.x+c0.x; f[1]=a0.y+c0.y; f[2]=a0.z+c0.z; f[3]=a0.w+c0.w;
                f[4]=a1.x+c1.x; f[5]=a1.y+c1.y; f[6]=a1.z+c1.z; f[7]=a1.w+c1.w;
            } else if (k < 512) {
                f[0]=fabsf(a0.x-c0.x); f[1]=fabsf(a0.y-c0.y); f[2]=fabsf(a0.z-c0.z); f[3]=fabsf(a0.w-c0.w);
                f[4]=fabsf(a1.x-c1.x); f[5]=fabsf(a1.y-c1.y); f[6]=fabsf(a1.z-c1.z); f[7]=fabsf(a1.w-c1.w);
            } else {
                f[0]=a0.x*c0.x; f[1]=a0.y*c0.y; f[2]=a0.z*c0.z; f[3]=a0.w*c0.w;
                f[4]=a1.x*c1.x; f[5]=a1.y*c1.y; f[6]=a1.z*c1.z; f[7]=a1.w*c1.w;
            }
        } else {
            const float* R = rel + (long)(p0 + pair) * D_R + (k - 768);
            float4 a0 = *(const float4*)R, a1 = *(const float4*)(R + 4);
            f[0]=a0.x; f[1]=a0.y; f[2]=a0.z; f[3]=a0.w;
            f[4]=a1.x; f[5]=a1.y; f[6]=a1.z; f[7]=a1.w;
        }
        uint4 pk;
        pk.x = pkbf2(f[0], f[1]);
        pk.y = pkbf2(f[2], f[3]);
        pk.z = pkbf2(f[4], f[5]);
        pk.w = pkbf2(f[6], f[7]);
        *(uint4*)&feats[pair * FS + k] = pk;
    }
    __syncthreads();

    const int w  = t >> 6;
    const int l  = t & 63;
    const int lr = l & 15, l4 = l >> 4;

    // phase 1: wave (kq = w&3, ng = w>>2): 3 n-frags x kc chunk {7,7,6,6}
    {
        const int kq = w & 3, ng = w >> 2;
        const int kc_lo = (kq < 2) ? kq * 7 : 14 + (kq - 2) * 6;
        const int kc_hi = (kq < 2) ? kc_lo + 7 : kc_lo + 6;
        f32x4 acc[3];
        acc[0] = (f32x4){0.f,0.f,0.f,0.f};
        acc[1] = (f32x4){0.f,0.f,0.f,0.f};
        acc[2] = (f32x4){0.f,0.f,0.f,0.f};
        const unsigned short* Arow = &feats[lr * FS + l4 * 8];
        for (int kc = kc_lo; kc < kc_hi; ++kc) {
            const s16x8 a = *(const s16x8*)(Arow + kc * 32);
            #pragma unroll
            for (int j = 0; j < 3; ++j) {
                const s16x8 bb = *(const s16x8*)(W1frag +
                    (((ng * 3 + j) * 26 + kc) * 64 + l) * 8);
                acc[j] = __builtin_amdgcn_mfma_f32_16x16x32_bf16(a, bb, acc[j], 0, 0, 0);
            }
        }
        #pragma unroll
        for (int j = 0; j < 3; ++j)
            #pragma unroll
            for (int r = 0; r < 4; ++r)
                y1part[kq][l4 * 4 + r][ng * 48 + j * 16 + lr] = acc[j][r];
    }
    __syncthreads();

    // phase 2: pairs 2w, 2w+1, one mf at a time (register-lean)
    float part[2][4];
    #pragma unroll
    for (int mf = 0; mf < 2; ++mf) {
        const int pl = 2 * w + mf;

        // 2a: A-fragments in consumer layout (row lr = b); sum 4 partials
        s16x8 afr[3];
        #pragma unroll
        for (int ks = 0; ks < 3; ++ks) {
            const int c = ks * 32 + l4 * 8;
            const float* gp = gqfrag + (ks * 64 + l) * 8;
            float4 g0 = *(const float4*)gp, g1 = *(const float4*)(gp + 4);
            float s0x=g0.x, s0y=g0.y, s0z=g0.z, s0w=g0.w;
            float s1x=g1.x, s1y=g1.y, s1z=g1.z, s1w=g1.w;
            #pragma unroll
            for (int kq = 0; kq < 4; ++kq) {
                const float* yp = &y1part[kq][pl][c];    // broadcast reads
                float4 u0 = *(const float4*)yp, u1 = *(const float4*)(yp + 4);
                s0x += u0.x; s0y += u0.y; s0z += u0.z; s0w += u0.w;
                s1x += u1.x; s1y += u1.y; s1z += u1.z; s1w += u1.w;
            }
            union { s16x8 v; uint32_t u[4]; } pk;
            pk.u[0] = pkbf2(gelu_f(s0x), gelu_f(s0y));
            pk.u[1] = pkbf2(gelu_f(s0z), gelu_f(s0w));
            pk.u[2] = pkbf2(gelu_f(s1x), gelu_f(s1y));
            pk.u[3] = pkbf2(gelu_f(s1z), gelu_f(s1w));
            afr[ks] = pk.v;
        }

        // 2b: layer-2 MFMA vs W2frag (L1/L2-hot), acc init = b2
        f32x4 acc2[6];
        #pragma unroll
        for (int nf = 0; nf < 6; ++nf) {
            const float bv = b2[nf * 16 + lr];
            acc2[nf] = (f32x4){bv, bv, bv, bv};
        }
        #pragma unroll
        for (int ks = 0; ks < 3; ++ks) {
            #pragma unroll
            for (int nf = 0; nf < 6; ++nf) {
                const s16x8 bb = *(const s16x8*)(W2frag + ((nf * 3 + ks) * 64 + l) * 8);
                acc2[nf] = __builtin_amdgcn_mfma_f32_16x16x32_bf16(afr[ks], bb, acc2[nf], 0, 0, 0);
            }
        }

        // 2c: gelu -> dot W3
        part[mf][0] = part[mf][1] = part[mf][2] = part[mf][3] = 0.f;
        #pragma unroll
        for (int nf = 0; nf < 6; ++nf) {
            const float wv = W3[nf * 16 + lr];
            #pragma unroll
            for (int r4 = 0; r4 < 4; ++r4)
                part[mf][r4] = __builtin_fmaf(gelu_f(acc2[nf][r4]), wv, part[mf][r4]);
        }
    }

    // reduce over 16 col-lanes -> store
    #pragma unroll
    for (int mask = 1; mask <= 8; mask <<= 1)
        #pragma unroll
        for (int mf = 0; mf < 2; ++mf)
            #pragma unroll
            for (int r4 = 0; r4 < 4; ++r4)
                part[mf][r4] += __shfl_xor(part[mf][r4], mask, 64);
    if (lr == 0) {
        const float b3v = b3[0];
        #pragma unroll
        for (int mf = 0; mf < 2; ++mf)
            #pragma unroll
            for (int r4 = 0; r4 < 4; ++r4)
                out[(l4 * 4 + r4) * P_N + p0 + 2 * w + mf] = part[mf][r4] + b3v;
    }
}

extern "C" void kernel_launch(void* const* d_in, const int* in_sizes, int n_in,
                              void* d_out, int out_size, void* d_ws, size_t ws_size,
                              hipStream_t stream)
{
    const float* g_q  = (const float*)d_in[0];
    const float* Phi  = (const float*)d_in[1];
    const int*   pidx = (const int*)d_in[2];
    const float* rel  = (const float*)d_in[3];
    const float* W1   = (const float*)d_in[4];
    const float* b1   = (const float*)d_in[5];
    const float* W2   = (const float*)d_in[6];
    const float* b2   = (const float*)d_in[7];
    const float* W3   = (const float*)d_in[8];
    const float* b3   = (const float*)d_in[9];
    float* out = (float*)d_out;

    char* ws = (char*)d_ws;
    float*          gqfrag = (float*)(ws + 0);               // 3*64*8 f32 = 6KB
    unsigned short* W1frag = (unsigned short*)(ws + 8192);   // 96*832*2
    unsigned short* W2frag = (unsigned short*)(ws + 167936); // 96*96*2

    hipLaunchKernelGGL(prep_kernel, dim3(364), dim3(256), 0, stream,
                       g_q, W1, b1, W2, gqfrag, W1frag, W2frag);
    hipLaunchKernelGGL(fused9_kernel, dim3(P_N / 16), dim3(512), 0, stream,
                       Phi, pidx, rel, W1frag, gqfrag, W2frag, b2, W3, b3, out);
}

// Round 13
// 42.922 us; speedup vs baseline: 1.5911x; 1.0265x over previous
//
#include <hip/hip_runtime.h>
#include <hip/hip_bf16.h>
#include <stdint.h>

static constexpr int P_N   = 16384;
static constexpr int D_Z   = 512;
static constexpr int D_PHI = 256;
static constexpr int D_R   = 64;
static constexpr int H     = 96;    // H1 == H2
static constexpr int KP    = 832;   // 3*D_PHI + D_R

using f32x4 = __attribute__((ext_vector_type(4))) float;
using s16x8 = __attribute__((ext_vector_type(8))) short;

__device__ __forceinline__ unsigned short f2bf(float f) {
    union { float f; uint32_t u; } v; v.f = f;
    return (unsigned short)((v.u + 0x7FFFu + ((v.u >> 16) & 1u)) >> 16);
}

// packed RNE f32x2 -> bf16x2 (v_cvt_pk_bf16_f32)
__device__ __forceinline__ uint32_t pkbf2(float lo, float hi) {
    union { __hip_bfloat162 h; uint32_t u; } c;
    c.h = __float22bfloat162_rn(make_float2(lo, hi));
    return c.u;
}

// gelu(x) ~= x * sigmoid(1.5957691*(x + 0.044715 x^3))
//         =  x * rcp(1 + exp2(x*(-2.3022126 - 0.1029444 x^2)))
__device__ __forceinline__ float gelu_f(float x) {
    float x2 = x * x;
    float u  = __builtin_fmaf(-0.1029444f, x2, -2.3022126f);
    float e  = __builtin_amdgcn_exp2f(x * u);
    return x * __builtin_amdgcn_rcpf(1.0f + e);
}

// ---------------------------------------------------------------------------
// prep: fragment-contiguous weight layouts so every consumer B-load is
//       base + lane*16B (fully coalesced).
//  blocks 0..15  : gqfrag[((n>>5)*64 + ((n>>3)&3)*16 + b)*8 + (n&7)]
//                  = g_q[b] @ W1[:512][n] + b1[n]     (f32)
//  blocks 16..327: W1frag[((nf*26+kc)*64 + l)*8 + ke] = bf16(W1[512+k][n])
//                  n = nf*16 + (l&15), k = kc*32 + (l>>4)*8 + ke
//  blocks 328..363: W2frag[((nf*3+ks)*64 + l)*8 + ke] = bf16(W2[k][n])
// ---------------------------------------------------------------------------
__global__ __launch_bounds__(256) void prep_kernel(
    const float* __restrict__ g_q, const float* __restrict__ W1,
    const float* __restrict__ b1, const float* __restrict__ W2,
    float* __restrict__ gqfrag, unsigned short* __restrict__ W1frag,
    unsigned short* __restrict__ W2frag)
{
    __shared__ float gql[D_Z];
    __shared__ float red[192];
    const int blk = blockIdx.x;
    const int t = threadIdx.x;
    if (blk < 16) {
        const int b = blk;
        for (int i = t; i < D_Z; i += 256) gql[i] = g_q[b * D_Z + i];
        __syncthreads();
        float acc = 0.f;
        if (t < 192) {
            const int n = t % 96, s = t / 96;
            const int k0 = s * 256;
            #pragma unroll 8
            for (int k = 0; k < 256; ++k)
                acc += gql[k0 + k] * W1[(k0 + k) * H + n];
            red[t] = acc;
        }
        __syncthreads();
        if (t < 96) {
            const float v = red[t] + red[t + 96] + b1[t];
            const int dst = ((t >> 5) * 64 + ((t >> 3) & 3) * 16 + b) * 8 + (t & 7);
            gqfrag[dst] = v;
        }
    } else if (blk < 328) {
        const int e = (blk - 16) * 256 + t;           // < 96*832
        const int n = e / KP, k = e % KP;
        const int nf = n >> 4, lr = n & 15;
        const int kc = k >> 5, l4 = (k >> 3) & 3, ke = k & 7;
        W1frag[((nf * 26 + kc) * 64 + l4 * 16 + lr) * 8 + ke] =
            f2bf(W1[(D_Z + k) * H + n]);
    } else {
        const int e = (blk - 328) * 256 + t;          // < 96*96
        const int n = e / H, k = e % H;
        const int nf = n >> 4, lr = n & 15;
        const int ks = k >> 5, l4 = (k >> 3) & 3, ke = k & 7;
        W2frag[((nf * 3 + ks) * 64 + l4 * 16 + lr) * 8 + ke] =
            f2bf(W2[k * H + n]);
    }
}

// ---------------------------------------------------------------------------
// fused11: 16 pairs x 16 b per 512-thr block (8 waves), grid 1024.
//  ph0 : ONE task per thread: pair p = t>>5, chunk c = t&31 -> load PI/PJ
//        8-elem chunks ONCE, write sum/|diff|/prod to feats[16][840] bf16.
//        Threads t<128 additionally copy rel chunks.
//  ph1 : waves 0..5 = (kh=w&1, ng=w>>1): TWO n-frags (nf = ng*2+j) x 13 kc;
//        partials -> y1part[kh][16][100] f32.  Waves 6,7 idle (short phase).
//  ph2 : wave w -> pairs 2w, 2w+1, one mf at a time (register-lean):
//        afr[3] = bf16(gelu(gq + y1h0 + y1h1)); 18 MFMA vs W2frag;
//        gelu -> dot W3; shfl-reduce -> out.
//  LDS 39.7KB -> 4 blocks/CU.
// ---------------------------------------------------------------------------
__global__ __launch_bounds__(512, 2) void fused11_kernel(
    const float* __restrict__ Phi, const int* __restrict__ pidx,
    const float* __restrict__ rel, const unsigned short* __restrict__ W1frag,
    const float* __restrict__ gqfrag, const unsigned short* __restrict__ W2frag,
    const float* __restrict__ b2, const float* __restrict__ W3,
    const float* __restrict__ b3, float* __restrict__ out)
{
    constexpr int FS = 840;                       // feats stride (shorts)
    __shared__ __align__(16) unsigned short feats[16 * FS];   // 26880 B
    __shared__ __align__(16) float y1part[2][16][100];        // 12800 B
    const int t = threadIdx.x;
    const int p0 = blockIdx.x * 16;

    // phase 0: one Phi-chunk task per thread (sum+diff+prod share loads)
    {
        const int p = t >> 5, c = t & 31, kb = c * 8;
        const int2 ij = *(const int2*)(pidx + 2 * (p0 + p));
        const float* PI = Phi + (long)ij.x * D_PHI + kb;
        const float* PJ = Phi + (long)ij.y * D_PHI + kb;
        float4 a0 = *(const float4*)PI, a1 = *(const float4*)(PI + 4);
        float4 c0 = *(const float4*)PJ, c1 = *(const float4*)(PJ + 4);
        uint4 s, d, q;
        s.x = pkbf2(a0.x + c0.x, a0.y + c0.y);
        s.y = pkbf2(a0.z + c0.z, a0.w + c0.w);
        s.z = pkbf2(a1.x + c1.x, a1.y + c1.y);
        s.w = pkbf2(a1.z + c1.z, a1.w + c1.w);
        d.x = pkbf2(fabsf(a0.x - c0.x), fabsf(a0.y - c0.y));
        d.y = pkbf2(fabsf(a0.z - c0.z), fabsf(a0.w - c0.w));
        d.z = pkbf2(fabsf(a1.x - c1.x), fabsf(a1.y - c1.y));
        d.w = pkbf2(fabsf(a1.z - c1.z), fabsf(a1.w - c1.w));
        q.x = pkbf2(a0.x * c0.x, a0.y * c0.y);
        q.y = pkbf2(a0.z * c0.z, a0.w * c0.w);
        q.z = pkbf2(a1.x * c1.x, a1.y * c1.y);
        q.w = pkbf2(a1.z * c1.z, a1.w * c1.w);
        *(uint4*)&feats[p * FS + kb]       = s;
        *(uint4*)&feats[p * FS + 256 + kb] = d;
        *(uint4*)&feats[p * FS + 512 + kb] = q;
        if (t < 128) {   // relation features: 16 pairs x 8 chunks
            const int p2 = t >> 3, c2 = t & 7;
            const float* R = rel + (long)(p0 + p2) * D_R + c2 * 8;
            float4 r0 = *(const float4*)R, r1 = *(const float4*)(R + 4);
            uint4 rr;
            rr.x = pkbf2(r0.x, r0.y); rr.y = pkbf2(r0.z, r0.w);
            rr.z = pkbf2(r1.x, r1.y); rr.w = pkbf2(r1.z, r1.w);
            *(uint4*)&feats[p2 * FS + 768 + c2 * 8] = rr;
        }
    }
    __syncthreads();

    const int w  = t >> 6;
    const int l  = t & 63;
    const int lr = l & 15, l4 = l >> 4;

    // phase 1: waves 0..5: (kh = w&1, ng = w>>1): 2 n-frags x 13 kc
    if (w < 6) {
        const int kh = w & 1, ng = w >> 1;       // ng in {0,1,2}
        const int kc0 = kh * 13;
        f32x4 acc[2];
        acc[0] = (f32x4){0.f,0.f,0.f,0.f};
        acc[1] = (f32x4){0.f,0.f,0.f,0.f};
        const unsigned short* Arow = &feats[lr * FS + l4 * 8];
        for (int kc = kc0; kc < kc0 + 13; ++kc) {
            const s16x8 a = *(const s16x8*)(Arow + kc * 32);
            #pragma unroll
            for (int j = 0; j < 2; ++j) {
                const s16x8 bb = *(const s16x8*)(W1frag +
                    (((ng * 2 + j) * 26 + kc) * 64 + l) * 8);
                acc[j] = __builtin_amdgcn_mfma_f32_16x16x32_bf16(a, bb, acc[j], 0, 0, 0);
            }
        }
        #pragma unroll
        for (int j = 0; j < 2; ++j)
            #pragma unroll
            for (int r = 0; r < 4; ++r)
                y1part[kh][l4 * 4 + r][ng * 32 + j * 16 + lr] = acc[j][r];
    }
    __syncthreads();

    // phase 2: pairs 2w, 2w+1, one mf at a time (register-lean)
    float part[2][4];
    #pragma unroll
    for (int mf = 0; mf < 2; ++mf) {
        const int pl = 2 * w + mf;

        // 2a: A-fragments in consumer layout (row lr = b); sum 2 partials
        s16x8 afr[3];
        #pragma unroll
        for (int ks = 0; ks < 3; ++ks) {
            const int c = ks * 32 + l4 * 8;
            const float* gp = gqfrag + (ks * 64 + l) * 8;
            float4 g0 = *(const float4*)gp, g1 = *(const float4*)(gp + 4);
            const float* ya = &y1part[0][pl][c];    // broadcast reads
            const float* yb = &y1part[1][pl][c];
            float4 u0 = *(const float4*)ya, u1 = *(const float4*)(ya + 4);
            float4 v0 = *(const float4*)yb, v1 = *(const float4*)(yb + 4);
            union { s16x8 v; uint32_t u[4]; } pk;
            pk.u[0] = pkbf2(gelu_f(g0.x + u0.x + v0.x), gelu_f(g0.y + u0.y + v0.y));
            pk.u[1] = pkbf2(gelu_f(g0.z + u0.z + v0.z), gelu_f(g0.w + u0.w + v0.w));
            pk.u[2] = pkbf2(gelu_f(g1.x + u1.x + v1.x), gelu_f(g1.y + u1.y + v1.y));
            pk.u[3] = pkbf2(gelu_f(g1.z + u1.z + v1.z), gelu_f(g1.w + u1.w + v1.w));
            afr[ks] = pk.v;
        }

        // 2b: layer-2 MFMA vs W2frag (L1-hot), acc init = b2
        f32x4 acc2[6];
        #pragma unroll
        for (int nf = 0; nf < 6; ++nf) {
            const float bv = b2[nf * 16 + lr];
            acc2[nf] = (f32x4){bv, bv, bv, bv};
        }
        #pragma unroll
        for (int ks = 0; ks < 3; ++ks) {
            #pragma unroll
            for (int nf = 0; nf < 6; ++nf) {
                const s16x8 bb = *(const s16x8*)(W2frag + ((nf * 3 + ks) * 64 + l) * 8);
                acc2[nf] = __builtin_amdgcn_mfma_f32_16x16x32_bf16(afr[ks], bb, acc2[nf], 0, 0, 0);
            }
        }

        // 2c: gelu -> dot W3
        part[mf][0] = part[mf][1] = part[mf][2] = part[mf][3] = 0.f;
        #pragma unroll
        for (int nf = 0; nf < 6; ++nf) {
            const float wv = W3[nf * 16 + lr];
            #pragma unroll
            for (int r4 = 0; r4 < 4; ++r4)
                part[mf][r4] = __builtin_fmaf(gelu_f(acc2[nf][r4]), wv, part[mf][r4]);
        }
    }

    // reduce over 16 col-lanes -> store
    #pragma unroll
    for (int mask = 1; mask <= 8; mask <<= 1)
        #pragma unroll
        for (int mf = 0; mf < 2; ++mf)
            #pragma unroll
            for (int r4 = 0; r4 < 4; ++r4)
                part[mf][r4] += __shfl_xor(part[mf][r4], mask, 64);
    if (lr == 0) {
        const float b3v = b3[0];
        #pragma unroll
        for (int mf = 0; mf < 2; ++mf)
            #pragma unroll
            for (int r4 = 0; r4 < 4; ++r4)
                out[(l4 * 4 + r4) * P_N + p0 + 2 * w + mf] = part[mf][r4] + b3v;
    }
}

extern "C" void kernel_launch(void* const* d_in, const int* in_sizes, int n_in,
                              void* d_out, int out_size, void* d_ws, size_t ws_size,
                              hipStream_t stream)
{
    const float* g_q  = (const float*)d_in[0];
    const float* Phi  = (const float*)d_in[1];
    const int*   pidx = (const int*)d_in[2];
    const float* rel  = (const float*)d_in[3];
    const float* W1   = (const float*)d_in[4];
    const float* b1   = (const float*)d_in[5];
    const float* W2   = (const float*)d_in[6];
    const float* b2   = (const float*)d_in[7];
    const float* W3   = (const float*)d_in[8];
    const float* b3   = (const float*)d_in[9];
    float* out = (float*)d_out;

    char* ws = (char*)d_ws;
    float*          gqfrag = (float*)(ws + 0);               // 3*64*8 f32 = 6KB
    unsigned short* W1frag = (unsigned short*)(ws + 8192);   // 96*832*2
    unsigned short* W2frag = (unsigned short*)(ws + 167936); // 96*96*2

    hipLaunchKernelGGL(prep_kernel, dim3(364), dim3(256), 0, stream,
                       g_q, W1, b1, W2, gqfrag, W1frag, W2frag);
    hipLaunchKernelGGL(fused11_kernel, dim3(P_N / 16), dim3(512), 0, stream,
                       Phi, pidx, rel, W1frag, gqfrag, W2frag, b2, W3, b3, out);
}

// Round 14
// 42.721 us; speedup vs baseline: 1.5985x; 1.0047x over previous
//
#include <hip/hip_runtime.h>
#include <hip/hip_bf16.h>
#include <stdint.h>

static constexpr int P_N   = 16384;
static constexpr int D_Z   = 512;
static constexpr int D_PHI = 256;
static constexpr int D_R   = 64;
static constexpr int H     = 96;    // H1 == H2
static constexpr int KP    = 832;   // 3*D_PHI + D_R

using f32x4 = __attribute__((ext_vector_type(4))) float;
using s16x8 = __attribute__((ext_vector_type(8))) short;

__device__ __forceinline__ unsigned short f2bf(float f) {
    union { float f; uint32_t u; } v; v.f = f;
    return (unsigned short)((v.u + 0x7FFFu + ((v.u >> 16) & 1u)) >> 16);
}

// packed RNE f32x2 -> bf16x2 (v_cvt_pk_bf16_f32)
__device__ __forceinline__ uint32_t pkbf2(float lo, float hi) {
    union { __hip_bfloat162 h; uint32_t u; } c;
    c.h = __float22bfloat162_rn(make_float2(lo, hi));
    return c.u;
}

// gelu(x) ~= x * sigmoid(1.5957691*(x + 0.044715 x^3))
//         =  x * rcp(1 + exp2(x*(-2.3022126 - 0.1029444 x^2)))
__device__ __forceinline__ float gelu_f(float x) {
    float x2 = x * x;
    float u  = __builtin_fmaf(-0.1029444f, x2, -2.3022126f);
    float e  = __builtin_amdgcn_exp2f(x * u);
    return x * __builtin_amdgcn_rcpf(1.0f + e);
}

// ---------------------------------------------------------------------------
// prep: fragment-contiguous weight layouts so every consumer B-load is
//       base + lane*16B (fully coalesced).
//  blocks 0..15  : gqfrag[((n>>5)*64 + ((n>>3)&3)*16 + b)*8 + (n&7)]
//                  = g_q[b] @ W1[:512][n] + b1[n]     (f32)
//  blocks 16..327: W1frag[((nf*26+kc)*64 + l)*8 + ke] = bf16(W1[512+k][n])
//                  n = nf*16 + (l&15), k = kc*32 + (l>>4)*8 + ke
//  blocks 328..363: W2frag[((nf*3+ks)*64 + l)*8 + ke] = bf16(W2[k][n])
// ---------------------------------------------------------------------------
__global__ __launch_bounds__(256) void prep_kernel(
    const float* __restrict__ g_q, const float* __restrict__ W1,
    const float* __restrict__ b1, const float* __restrict__ W2,
    float* __restrict__ gqfrag, unsigned short* __restrict__ W1frag,
    unsigned short* __restrict__ W2frag)
{
    __shared__ float gql[D_Z];
    __shared__ float red[192];
    const int blk = blockIdx.x;
    const int t = threadIdx.x;
    if (blk < 16) {
        const int b = blk;
        for (int i = t; i < D_Z; i += 256) gql[i] = g_q[b * D_Z + i];
        __syncthreads();
        float acc = 0.f;
        if (t < 192) {
            const int n = t % 96, s = t / 96;
            const int k0 = s * 256;
            #pragma unroll 8
            for (int k = 0; k < 256; ++k)
                acc += gql[k0 + k] * W1[(k0 + k) * H + n];
            red[t] = acc;
        }
        __syncthreads();
        if (t < 96) {
            const float v = red[t] + red[t + 96] + b1[t];
            const int dst = ((t >> 5) * 64 + ((t >> 3) & 3) * 16 + b) * 8 + (t & 7);
            gqfrag[dst] = v;
        }
    } else if (blk < 328) {
        const int e = (blk - 16) * 256 + t;           // < 96*832
        const int n = e / KP, k = e % KP;
        const int nf = n >> 4, lr = n & 15;
        const int kc = k >> 5, l4 = (k >> 3) & 3, ke = k & 7;
        W1frag[((nf * 26 + kc) * 64 + l4 * 16 + lr) * 8 + ke] =
            f2bf(W1[(D_Z + k) * H + n]);
    } else {
        const int e = (blk - 328) * 256 + t;          // < 96*96
        const int n = e / H, k = e % H;
        const int nf = n >> 4, lr = n & 15;
        const int ks = k >> 5, l4 = (k >> 3) & 3, ke = k & 7;
        W2frag[((nf * 3 + ks) * 64 + l4 * 16 + lr) * 8 + ke] =
            f2bf(W2[k * H + n]);
    }
}

// ---------------------------------------------------------------------------
// fused12: 16 pairs x 16 b per 512-thr block (8 waves), grid 1024.
//  ph0 : ONE task per thread: pair p = t>>5, chunk c = t&31 -> load PI/PJ
//        8-elem chunks ONCE, write sum/|diff|/prod to feats[16][840] bf16.
//        Threads t<128 additionally copy rel chunks.
//  ph1 : waves 0..5 = (kh=w&1, ng=w>>1): TWO n-frags (nf = ng*2+j) x 13 kc
//        -> y1part[kh][16][100].  Waves 6,7 (previously idle): stage
//        W2frag (18KB) + gqfrag (6KB) into LDS — hidden under ph1 MFMA.
//  ph2 : wave w -> pairs 2w, 2w+1, one mf at a time (register-lean):
//        afr[3] = bf16(gelu(gq + y1h0 + y1h1)); 18 MFMA with B from LDS;
//        gelu -> dot W3; shfl-reduce -> out.
//  LDS 64.3KB -> 2 blocks/CU (matches the 68-VGPR wave cap; no loss).
// ---------------------------------------------------------------------------
__global__ __launch_bounds__(512, 2) void fused12_kernel(
    const float* __restrict__ Phi, const int* __restrict__ pidx,
    const float* __restrict__ rel, const unsigned short* __restrict__ W1frag,
    const float* __restrict__ gqfrag, const unsigned short* __restrict__ W2frag,
    const float* __restrict__ b2, const float* __restrict__ W3,
    const float* __restrict__ b3, float* __restrict__ out)
{
    constexpr int FS = 840;                       // feats stride (shorts)
    __shared__ __align__(16) unsigned short feats[16 * FS];   // 26880 B
    __shared__ __align__(16) float y1part[2][16][100];        // 12800 B
    __shared__ __align__(16) unsigned short w2s[6 * 3 * 64 * 8]; // 18432 B
    __shared__ __align__(16) float gqs[3 * 64 * 8];           // 6144 B
    const int t = threadIdx.x;
    const int p0 = blockIdx.x * 16;

    // phase 0: one Phi-chunk task per thread (sum+diff+prod share loads)
    {
        const int p = t >> 5, c = t & 31, kb = c * 8;
        const int2 ij = *(const int2*)(pidx + 2 * (p0 + p));
        const float* PI = Phi + (long)ij.x * D_PHI + kb;
        const float* PJ = Phi + (long)ij.y * D_PHI + kb;
        float4 a0 = *(const float4*)PI, a1 = *(const float4*)(PI + 4);
        float4 c0 = *(const float4*)PJ, c1 = *(const float4*)(PJ + 4);
        uint4 s, d, q;
        s.x = pkbf2(a0.x + c0.x, a0.y + c0.y);
        s.y = pkbf2(a0.z + c0.z, a0.w + c0.w);
        s.z = pkbf2(a1.x + c1.x, a1.y + c1.y);
        s.w = pkbf2(a1.z + c1.z, a1.w + c1.w);
        d.x = pkbf2(fabsf(a0.x - c0.x), fabsf(a0.y - c0.y));
        d.y = pkbf2(fabsf(a0.z - c0.z), fabsf(a0.w - c0.w));
        d.z = pkbf2(fabsf(a1.x - c1.x), fabsf(a1.y - c1.y));
        d.w = pkbf2(fabsf(a1.z - c1.z), fabsf(a1.w - c1.w));
        q.x = pkbf2(a0.x * c0.x, a0.y * c0.y);
        q.y = pkbf2(a0.z * c0.z, a0.w * c0.w);
        q.z = pkbf2(a1.x * c1.x, a1.y * c1.y);
        q.w = pkbf2(a1.z * c1.z, a1.w * c1.w);
        *(uint4*)&feats[p * FS + kb]       = s;
        *(uint4*)&feats[p * FS + 256 + kb] = d;
        *(uint4*)&feats[p * FS + 512 + kb] = q;
        if (t < 128) {   // relation features: 16 pairs x 8 chunks
            const int p2 = t >> 3, c2 = t & 7;
            const float* R = rel + (long)(p0 + p2) * D_R + c2 * 8;
            float4 r0 = *(const float4*)R, r1 = *(const float4*)(R + 4);
            uint4 rr;
            rr.x = pkbf2(r0.x, r0.y); rr.y = pkbf2(r0.z, r0.w);
            rr.z = pkbf2(r1.x, r1.y); rr.w = pkbf2(r1.z, r1.w);
            *(uint4*)&feats[p2 * FS + 768 + c2 * 8] = rr;
        }
    }
    __syncthreads();

    const int w  = t >> 6;
    const int l  = t & 63;
    const int lr = l & 15, l4 = l >> 4;

    // phase 1: waves 0..5: (kh = w&1, ng = w>>1): 2 n-frags x 13 kc
    //          waves 6..7: stage W2frag + gqfrag into LDS (hidden copy)
    if (w < 6) {
        const int kh = w & 1, ng = w >> 1;       // ng in {0,1,2}
        const int kc0 = kh * 13;
        f32x4 acc[2];
        acc[0] = (f32x4){0.f,0.f,0.f,0.f};
        acc[1] = (f32x4){0.f,0.f,0.f,0.f};
        const unsigned short* Arow = &feats[lr * FS + l4 * 8];
        for (int kc = kc0; kc < kc0 + 13; ++kc) {
            const s16x8 a = *(const s16x8*)(Arow + kc * 32);
            #pragma unroll
            for (int j = 0; j < 2; ++j) {
                const s16x8 bb = *(const s16x8*)(W1frag +
                    (((ng * 2 + j) * 26 + kc) * 64 + l) * 8);
                acc[j] = __builtin_amdgcn_mfma_f32_16x16x32_bf16(a, bb, acc[j], 0, 0, 0);
            }
        }
        #pragma unroll
        for (int j = 0; j < 2; ++j)
            #pragma unroll
            for (int r = 0; r < 4; ++r)
                y1part[kh][l4 * 4 + r][ng * 32 + j * 16 + lr] = acc[j][r];
    } else {
        const int tl = t - 384;                  // 0..127
        uint4*       w2d = (uint4*)w2s;
        const uint4* w2g = (const uint4*)W2frag;
        #pragma unroll
        for (int i = 0; i < 9; ++i)              // 1152 uint4 = 18KB
            w2d[tl + i * 128] = w2g[tl + i * 128];
        uint4*       gqd = (uint4*)gqs;
        const uint4* gqg = (const uint4*)gqfrag;
        #pragma unroll
        for (int i = 0; i < 3; ++i)              // 384 uint4 = 6KB
            gqd[tl + i * 128] = gqg[tl + i * 128];
    }
    __syncthreads();

    // phase 2: pairs 2w, 2w+1, one mf at a time (register-lean)
    float part[2][4];
    #pragma unroll
    for (int mf = 0; mf < 2; ++mf) {
        const int pl = 2 * w + mf;

        // 2a: A-fragments in consumer layout (row lr = b); sum 2 partials
        s16x8 afr[3];
        #pragma unroll
        for (int ks = 0; ks < 3; ++ks) {
            const int c = ks * 32 + l4 * 8;
            const float* gp = gqs + (ks * 64 + l) * 8;
            float4 g0 = *(const float4*)gp, g1 = *(const float4*)(gp + 4);
            const float* ya = &y1part[0][pl][c];    // broadcast reads
            const float* yb = &y1part[1][pl][c];
            float4 u0 = *(const float4*)ya, u1 = *(const float4*)(ya + 4);
            float4 v0 = *(const float4*)yb, v1 = *(const float4*)(yb + 4);
            union { s16x8 v; uint32_t u[4]; } pk;
            pk.u[0] = pkbf2(gelu_f(g0.x + u0.x + v0.x), gelu_f(g0.y + u0.y + v0.y));
            pk.u[1] = pkbf2(gelu_f(g0.z + u0.z + v0.z), gelu_f(g0.w + u0.w + v0.w));
            pk.u[2] = pkbf2(gelu_f(g1.x + u1.x + v1.x), gelu_f(g1.y + u1.y + v1.y));
            pk.u[3] = pkbf2(gelu_f(g1.z + u1.z + v1.z), gelu_f(g1.w + u1.w + v1.w));
            afr[ks] = pk.v;
        }

        // 2b: layer-2 MFMA, B from LDS (w2s), acc init = b2
        f32x4 acc2[6];
        #pragma unroll
        for (int nf = 0; nf < 6; ++nf) {
            const float bv = b2[nf * 16 + lr];
            acc2[nf] = (f32x4){bv, bv, bv, bv};
        }
        #pragma unroll
        for (int ks = 0; ks < 3; ++ks) {
            #pragma unroll
            for (int nf = 0; nf < 6; ++nf) {
                const s16x8 bb = *(const s16x8*)&w2s[((nf * 3 + ks) * 64 + l) * 8];
                acc2[nf] = __builtin_amdgcn_mfma_f32_16x16x32_bf16(afr[ks], bb, acc2[nf], 0, 0, 0);
            }
        }

        // 2c: gelu -> dot W3
        part[mf][0] = part[mf][1] = part[mf][2] = part[mf][3] = 0.f;
        #pragma unroll
        for (int nf = 0; nf < 6; ++nf) {
            const float wv = W3[nf * 16 + lr];
            #pragma unroll
            for (int r4 = 0; r4 < 4; ++r4)
                part[mf][r4] = __builtin_fmaf(gelu_f(acc2[nf][r4]), wv, part[mf][r4]);
        }
    }

    // reduce over 16 col-lanes -> store
    #pragma unroll
    for (int mask = 1; mask <= 8; mask <<= 1)
        #pragma unroll
        for (int mf = 0; mf < 2; ++mf)
            #pragma unroll
            for (int r4 = 0; r4 < 4; ++r4)
                part[mf][r4] += __shfl_xor(part[mf][r4], mask, 64);
    if (lr == 0) {
        const float b3v = b3[0];
        #pragma unroll
        for (int mf = 0; mf < 2; ++mf)
            #pragma unroll
            for (int r4 = 0; r4 < 4; ++r4)
                out[(l4 * 4 + r4) * P_N + p0 + 2 * w + mf] = part[mf][r4] + b3v;
    }
}

extern "C" void kernel_launch(void* const* d_in, const int* in_sizes, int n_in,
                              void* d_out, int out_size, void* d_ws, size_t ws_size,
                              hipStream_t stream)
{
    const float* g_q  = (const float*)d_in[0];
    const float* Phi  = (const float*)d_in[1];
    const int*   pidx = (const int*)d_in[2];
    const float* rel  = (const float*)d_in[3];
    const float* W1   = (const float*)d_in[4];
    const float* b1   = (const float*)d_in[5];
    const float* W2   = (const float*)d_in[6];
    const float* b2   = (const float*)d_in[7];
    const float* W3   = (const float*)d_in[8];
    const float* b3   = (const float*)d_in[9];
    float* out = (float*)d_out;

    char* ws = (char*)d_ws;
    float*          gqfrag = (float*)(ws + 0);               // 3*64*8 f32 = 6KB
    unsigned short* W1frag = (unsigned short*)(ws + 8192);   // 96*832*2
    unsigned short* W2frag = (unsigned short*)(ws + 167936); // 96*96*2

    hipLaunchKernelGGL(prep_kernel, dim3(364), dim3(256), 0, stream,
                       g_q, W1, b1, W2, gqfrag, W1frag, W2frag);
    hipLaunchKernelGGL(fused12_kernel, dim3(P_N / 16), dim3(512), 0, stream,
                       Phi, pidx, rel, W1frag, gqfrag, W2frag, b2, W3, b3, out);
}